// Round 1
// baseline (695.568 us; speedup 1.0000x reference)
//
#include <hip/hip_runtime.h>
#include <hip/hip_bf16.h>
#include <stdint.h>

// Problem constants (from reference): B=8, T=256, S=400, H=512, VOCAB=32000
#define BB 8
#define TT 256
#define SS 400
#define HH 512
#define VV 32000
#define MM (BB*TT)      // 2048 rows
#define KK 512          // shared K for both GEMMs

typedef __bf16 bf16x8 __attribute__((ext_vector_type(8)));
typedef float  f32x4  __attribute__((ext_vector_type(4)));

__device__ __forceinline__ unsigned short f2bf(float x) {
    union { float f; unsigned u; } v; v.f = x;
    unsigned r = v.u + 0x7fffu + ((v.u >> 16) & 1u);   // RNE
    return (unsigned short)(r >> 16);
}

__device__ __forceinline__ void async_load16(const void* g, void* lds) {
    __builtin_amdgcn_global_load_lds(
        (const __attribute__((address_space(1))) unsigned int*)g,
        (__attribute__((address_space(3))) unsigned int*)lds,
        16, 0, 0);
}

// ---------------- elementwise fp32 -> bf16 ----------------
__global__ __launch_bounds__(256) void f32_to_bf16_kernel(const float* __restrict__ x,
                                                          unsigned short* __restrict__ y, int n4) {
    int i = blockIdx.x * blockDim.x + threadIdx.x;
    if (i < n4) {
        float4 v = ((const float4*)x)[i];
        ushort4 o;
        o.x = f2bf(v.x); o.y = f2bf(v.y); o.z = f2bf(v.z); o.w = f2bf(v.w);
        ((ushort4*)y)[i] = o;
    }
}

// ---------------- transpose (K x N fp32) -> (N x K bf16) ----------------
__global__ __launch_bounds__(256) void transpose_bf16_kernel(const float* __restrict__ W,
                                                             unsigned short* __restrict__ Wt,
                                                             int K, int N) {
    __shared__ float tile[32][33];
    int n0 = blockIdx.x * 32, k0 = blockIdx.y * 32;
    int t = threadIdx.x;
    int r  = t >> 3;          // 0..31
    int c4 = (t & 7) * 4;     // 0,4,...,28
    float4 v = *(const float4*)(W + (size_t)(k0 + r) * N + n0 + c4);
    tile[r][c4 + 0] = v.x; tile[r][c4 + 1] = v.y;
    tile[r][c4 + 2] = v.z; tile[r][c4 + 3] = v.w;
    __syncthreads();
    ushort4 o;
    o.x = f2bf(tile[c4 + 0][r]);
    o.y = f2bf(tile[c4 + 1][r]);
    o.z = f2bf(tile[c4 + 2][r]);
    o.w = f2bf(tile[c4 + 3][r]);
    *(ushort4*)(Wt + (size_t)(n0 + r) * K + k0 + c4) = o;
}

// ---------------- p_gen: sigmoid(state_input @ w_pgen + b) ----------------
__global__ __launch_bounds__(256) void pgen_kernel(const float* __restrict__ state,
                                                   const float* __restrict__ wp,
                                                   const float* __restrict__ bp,
                                                   float* __restrict__ pg) {
    int row  = blockIdx.x * 4 + (threadIdx.x >> 6);
    int lane = threadIdx.x & 63;
    const float* s = state + (size_t)row * (2 * HH);
    float acc = 0.f;
    for (int j = lane; j < 2 * HH; j += 64) acc += s[j] * wp[j];
    for (int off = 32; off; off >>= 1) acc += __shfl_xor(acc, off, 64);
    if (lane == 0) pg[row] = 1.f / (1.f + __expf(-(acc + bp[0])));
}

// ---------------- m97-style bf16 MFMA GEMM: C = A(MxK) * Bt(NxK)^T + bias ----------------
template <bool OUT_BF16>
__global__ __launch_bounds__(256) void gemm_bt_kernel(const unsigned short* __restrict__ A,
                                                      const unsigned short* __restrict__ Bt,
                                                      const float* __restrict__ bias,
                                                      void* __restrict__ out,
                                                      int N) {
    __shared__ __align__(16) unsigned short As[128 * 32];
    __shared__ __align__(16) unsigned short Bs[128 * 32];
    const int tid  = threadIdx.x;
    const int wave = tid >> 6;
    const int lane = tid & 63;
    const int m0 = blockIdx.y * 128, n0 = blockIdx.x * 128;
    const int q  = lane >> 4;       // quad 0..3
    const int r_ = lane & 15;       // 0..15
    const int wm = (wave >> 1) * 64, wn = (wave & 1) * 64;

    f32x4 acc[4][4] = {};

    for (int k0 = 0; k0 < KK; k0 += 32) {
        // stage A and Bt tiles (128 rows x 32 cols bf16 each): 512 16B-chunks per tile
        #pragma unroll
        for (int rr = 0; rr < 2; ++rr) {
            int cc  = tid + rr * 256;
            int row = cc >> 2;
            int col = (cc & 3) * 8;
            async_load16(A  + (size_t)(m0 + row) * KK + k0 + col, (char*)As + (size_t)cc * 16);
            async_load16(Bt + (size_t)(n0 + row) * KK + k0 + col, (char*)Bs + (size_t)cc * 16);
        }
        __syncthreads();

        bf16x8 a[4], b[4];
        #pragma unroll
        for (int i = 0; i < 4; ++i) {
            a[i] = *(const bf16x8*)(As + (wm + i * 16 + r_) * 32 + q * 8);
            b[i] = *(const bf16x8*)(Bs + (wn + i * 16 + r_) * 32 + q * 8);
        }
        #pragma unroll
        for (int mi = 0; mi < 4; ++mi)
            #pragma unroll
            for (int ni = 0; ni < 4; ++ni)
                acc[mi][ni] = __builtin_amdgcn_mfma_f32_16x16x32_bf16(a[mi], b[ni], acc[mi][ni], 0, 0, 0);
        __syncthreads();
    }

    // epilogue: D[m][n], col(n)=lane&15, row(m)=quad*4+reg (verified mapping)
    #pragma unroll
    for (int mi = 0; mi < 4; ++mi) {
        #pragma unroll
        for (int ni = 0; ni < 4; ++ni) {
            int n = n0 + wn + ni * 16 + r_;
            float bv = bias[n];
            #pragma unroll
            for (int rg = 0; rg < 4; ++rg) {
                int m = m0 + wm + mi * 16 + q * 4 + rg;
                float v = acc[mi][ni][rg] + bv;
                if (OUT_BF16)
                    ((unsigned short*)out)[(size_t)m * N + n] = f2bf(v);
                else
                    ((float*)out)[(size_t)m * N + n] = v;
            }
        }
    }
}

// ---------------- per-row sum of exp(logits) ----------------
__global__ __launch_bounds__(256) void zreduce_kernel(const float* __restrict__ logits,
                                                      float* __restrict__ Z) {
    int row = blockIdx.x;
    const float* p = logits + (size_t)row * VV;
    float s = 0.f;
    for (int j = threadIdx.x; j < VV; j += 256) s += __expf(p[j]);
    int lane = threadIdx.x & 63, wave = threadIdx.x >> 6;
    for (int off = 32; off; off >>= 1) s += __shfl_xor(s, off, 64);
    __shared__ float red[4];
    if (lane == 0) red[wave] = s;
    __syncthreads();
    if (threadIdx.x == 0) Z[row] = red[0] + red[1] + red[2] + red[3];
}

// ---------------- finalize: scatter-add attn + log, in place over logits ----------------
__global__ __launch_bounds__(256) void finalize_kernel(float* __restrict__ logits,
                                                       const float* __restrict__ pg_arr,
                                                       const float* __restrict__ Z,
                                                       const float* __restrict__ attn,
                                                       const int* __restrict__ enc) {
    constexpr int CH = VV / 4;  // 8000 columns per block
    __shared__ float acc[CH];
    int bid  = blockIdx.x;
    int row  = bid >> 2;
    int part = bid & 3;
    int nbase = part * CH;
    for (int j = threadIdx.x; j < CH; j += 256) acc[j] = 0.f;
    float pg    = pg_arr[row];
    float scale = pg / Z[row];
    float om    = 1.f - pg;
    int batch   = row / TT;
    __syncthreads();
    for (int s = threadIdx.x; s < SS; s += 256) {
        int idx = enc[batch * SS + s];
        if (idx >= nbase && idx < nbase + CH)
            atomicAdd(&acc[idx - nbase], om * attn[(size_t)row * SS + s]);
    }
    __syncthreads();
    float* p = logits + (size_t)row * VV + nbase;
    for (int j = threadIdx.x; j < CH; j += 256) {
        float v = scale * __expf(p[j]) + acc[j] + 1e-12f;
        p[j] = __logf(v);
    }
}

extern "C" void kernel_launch(void* const* d_in, const int* in_sizes, int n_in,
                              void* d_out, int out_size, void* d_ws, size_t ws_size,
                              hipStream_t stream) {
    const float* s_output  = (const float*)d_in[0];   // (2048, 512)
    const float* state_in  = (const float*)d_in[1];   // (2048, 1024)
    const float* attn      = (const float*)d_in[2];   // (2048, 400)
    const int*   enc       = (const int*)  d_in[3];   // (8, 400)
    const float* w_pgen    = (const float*)d_in[4];   // (1024, 1)
    const float* b_pgen    = (const float*)d_in[5];   // (1,)
    const float* w1        = (const float*)d_in[6];   // (512, 512)
    const float* b1        = (const float*)d_in[7];   // (512,)
    const float* w2        = (const float*)d_in[8];   // (512, 32000)
    const float* b2        = (const float*)d_in[9];   // (32000,)

    // workspace layout (bytes)
    char* ws = (char*)d_ws;
    float*          pg     = (float*)(ws + 0);                        // 2048 f32
    float*          Z      = (float*)(ws + 8192);                     // 2048 f32
    unsigned short* hidden = (unsigned short*)(ws + 16384);           // 2048x512 bf16
    unsigned short* sA     = (unsigned short*)(ws + 2113536);         // 2048x512 bf16
    unsigned short* w1t    = (unsigned short*)(ws + 4210688);         // 512x512 bf16 (N x K)
    unsigned short* w2t    = (unsigned short*)(ws + 4734976);         // 32000x512 bf16 (N x K)

    // 1. converts / transposes
    f32_to_bf16_kernel<<<(MM * HH / 4 + 255) / 256, 256, 0, stream>>>(s_output, sA, MM * HH / 4);
    transpose_bf16_kernel<<<dim3(HH / 32, KK / 32), 256, 0, stream>>>(w1, w1t, KK, HH);
    transpose_bf16_kernel<<<dim3(VV / 32, KK / 32), 256, 0, stream>>>(w2, w2t, KK, VV);

    // 2. p_gen
    pgen_kernel<<<MM / 4, 256, 0, stream>>>(state_in, w_pgen, b_pgen, pg);

    // 3. hidden = bf16(s_output @ w1 + b1)
    gemm_bt_kernel<true><<<dim3(HH / 128, MM / 128), 256, 0, stream>>>(sA, w1t, b1, hidden, HH);

    // 4. logits = hidden @ w2 + b2  (fp32, into d_out)
    gemm_bt_kernel<false><<<dim3(VV / 128, MM / 128), 256, 0, stream>>>(hidden, w2t, b2, d_out, VV);

    // 5. Z[row] = sum_j exp(logits[row][j])
    zreduce_kernel<<<MM, 256, 0, stream>>>((const float*)d_out, Z);

    // 6. final: log(p_gen*softmax + (1-p_gen)*scatter(attn) + 1e-12), in place
    finalize_kernel<<<MM * 4, 256, 0, stream>>>((float*)d_out, pg, Z, attn, enc);
}

// Round 3
// 552.793 us; speedup vs baseline: 1.2583x; 1.2583x over previous
//
#include <hip/hip_runtime.h>
#include <hip/hip_bf16.h>
#include <stdint.h>

// Problem constants: B=8, T=256, S=400, H=512, VOCAB=32000
#define BB 8
#define TT 256
#define SS 400
#define HH 512
#define VV 32000
#define MM (BB*TT)      // 2048 rows
#define KK 512
#define NBLK (VV/128)   // 250 n-blocks in gemm2

typedef __bf16 bf16x8 __attribute__((ext_vector_type(8)));
typedef float  f32x4  __attribute__((ext_vector_type(4)));
typedef unsigned short ushort8 __attribute__((ext_vector_type(8)));

__device__ __forceinline__ unsigned short f2bf(float x) {
    union { float f; unsigned u; } v; v.f = x;
    unsigned r = v.u + 0x7fffu + ((v.u >> 16) & 1u);   // RNE
    return (unsigned short)(r >> 16);
}
__device__ __forceinline__ float bf2f(unsigned short u) {
    union { unsigned u; float f; } v; v.u = ((unsigned)u) << 16; return v.f;
}

__device__ __forceinline__ void async_ld16(const void* g, void* lds) {
    __builtin_amdgcn_global_load_lds(
        (const __attribute__((address_space(1))) unsigned int*)g,
        (__attribute__((address_space(3))) unsigned int*)lds,
        16, 0, 0);
}

// ---------------- elementwise fp32 -> bf16 ----------------
__global__ __launch_bounds__(256) void f32_to_bf16_kernel(const float* __restrict__ x,
                                                          unsigned short* __restrict__ y, int n4) {
    int i = blockIdx.x * blockDim.x + threadIdx.x;
    if (i < n4) {
        float4 v = ((const float4*)x)[i];
        ushort4 o;
        o.x = f2bf(v.x); o.y = f2bf(v.y); o.z = f2bf(v.z); o.w = f2bf(v.w);
        ((ushort4*)y)[i] = o;
    }
}

// ---------------- transpose (K x N fp32) -> (N x K bf16) ----------------
__global__ __launch_bounds__(256) void transpose_bf16_kernel(const float* __restrict__ W,
                                                             unsigned short* __restrict__ Wt,
                                                             int K, int N) {
    __shared__ float tile[32][33];
    int n0 = blockIdx.x * 32, k0 = blockIdx.y * 32;
    int t = threadIdx.x;
    int r  = t >> 3;          // 0..31
    int c4 = (t & 7) * 4;     // 0,4,...,28
    float4 v = *(const float4*)(W + (size_t)(k0 + r) * N + n0 + c4);
    tile[r][c4 + 0] = v.x; tile[r][c4 + 1] = v.y;
    tile[r][c4 + 2] = v.z; tile[r][c4 + 3] = v.w;
    __syncthreads();
    ushort4 o;
    o.x = f2bf(tile[c4 + 0][r]);
    o.y = f2bf(tile[c4 + 1][r]);
    o.z = f2bf(tile[c4 + 2][r]);
    o.w = f2bf(tile[c4 + 3][r]);
    *(ushort4*)(Wt + (size_t)(n0 + r) * K + k0 + c4) = o;
}

// ---------------- p_gen ----------------
__global__ __launch_bounds__(256) void pgen_kernel(const float* __restrict__ state,
                                                   const float* __restrict__ wp,
                                                   const float* __restrict__ bp,
                                                   float* __restrict__ pg) {
    int row  = blockIdx.x * 4 + (threadIdx.x >> 6);
    int lane = threadIdx.x & 63;
    const float* s = state + (size_t)row * (2 * HH);
    float acc = 0.f;
    for (int j = lane; j < 2 * HH; j += 64) acc += s[j] * wp[j];
    for (int off = 32; off; off >>= 1) acc += __shfl_xor(acc, off, 64);
    if (lane == 0) pg[row] = 1.f / (1.f + __expf(-(acc + bp[0])));
}

// ---------------- GEMM1: hidden = bf16(A @ W1t^T + b1) ----------------
__global__ __launch_bounds__(256) void gemm1_kernel(const unsigned short* __restrict__ A,
                                                    const unsigned short* __restrict__ Bt,
                                                    const float* __restrict__ bias,
                                                    unsigned short* __restrict__ out, int N) {
    __shared__ __align__(16) unsigned short As[128 * 32];
    __shared__ __align__(16) unsigned short Bs[128 * 32];
    const int tid = threadIdx.x, wave = tid >> 6, lane = tid & 63;
    const int m0 = blockIdx.y * 128, n0 = blockIdx.x * 128;
    const int q = lane >> 4, r_ = lane & 15;
    const int wm = (wave >> 1) * 64, wn = (wave & 1) * 64;
    f32x4 acc[4][4] = {};
    for (int k0 = 0; k0 < KK; k0 += 32) {
        #pragma unroll
        for (int rr = 0; rr < 2; ++rr) {
            int cc = tid + rr * 256, row = cc >> 2, col = (cc & 3) * 8;
            async_ld16(A  + (size_t)(m0 + row) * KK + k0 + col, (char*)As + (size_t)cc * 16);
            async_ld16(Bt + (size_t)(n0 + row) * KK + k0 + col, (char*)Bs + (size_t)cc * 16);
        }
        __syncthreads();
        bf16x8 a[4], b[4];
        #pragma unroll
        for (int i = 0; i < 4; ++i) {
            a[i] = *(const bf16x8*)(As + (wm + i * 16 + r_) * 32 + q * 8);
            b[i] = *(const bf16x8*)(Bs + (wn + i * 16 + r_) * 32 + q * 8);
        }
        #pragma unroll
        for (int mi = 0; mi < 4; ++mi)
            #pragma unroll
            for (int ni = 0; ni < 4; ++ni)
                acc[mi][ni] = __builtin_amdgcn_mfma_f32_16x16x32_bf16(a[mi], b[ni], acc[mi][ni], 0, 0, 0);
        __syncthreads();
    }
    #pragma unroll
    for (int mi = 0; mi < 4; ++mi)
        #pragma unroll
        for (int ni = 0; ni < 4; ++ni) {
            int n = n0 + wn + ni * 16 + r_;
            float bv = bias[n];
            #pragma unroll
            for (int rg = 0; rg < 4; ++rg) {
                int m = m0 + wm + mi * 16 + q * 4 + rg;
                out[(size_t)m * N + n] = f2bf(acc[mi][ni][rg] + bv);
            }
        }
}

// ---------------- GEMM2 + exp epilogue + per-block row sums ----------------
// E[m][n] = exp(hidden@w2t^T + b2); Zpart[nblk][m] = sum over this block's 128 cols.
template <bool E_BF16>
__global__ __launch_bounds__(256) void gemm2_exp_kernel(const unsigned short* __restrict__ A,
                                                        const unsigned short* __restrict__ Bt,
                                                        const float* __restrict__ bias,
                                                        void* __restrict__ E,
                                                        float* __restrict__ Zpart) {
    __shared__ __align__(16) unsigned short As[128 * 32];
    __shared__ __align__(16) unsigned short Bs[128 * 32];
    __shared__ float rowsum[128];
    const int tid = threadIdx.x, wave = tid >> 6, lane = tid & 63;
    const int m0 = blockIdx.y * 128, n0 = blockIdx.x * 128;
    const int q = lane >> 4, r_ = lane & 15;
    const int wm = (wave >> 1) * 64, wn = (wave & 1) * 64;
    f32x4 acc[4][4] = {};
    for (int k0 = 0; k0 < KK; k0 += 32) {
        #pragma unroll
        for (int rr = 0; rr < 2; ++rr) {
            int cc = tid + rr * 256, row = cc >> 2, col = (cc & 3) * 8;
            async_ld16(A  + (size_t)(m0 + row) * KK + k0 + col, (char*)As + (size_t)cc * 16);
            async_ld16(Bt + (size_t)(n0 + row) * KK + k0 + col, (char*)Bs + (size_t)cc * 16);
        }
        __syncthreads();
        bf16x8 a[4], b[4];
        #pragma unroll
        for (int i = 0; i < 4; ++i) {
            a[i] = *(const bf16x8*)(As + (wm + i * 16 + r_) * 32 + q * 8);
            b[i] = *(const bf16x8*)(Bs + (wn + i * 16 + r_) * 32 + q * 8);
        }
        #pragma unroll
        for (int mi = 0; mi < 4; ++mi)
            #pragma unroll
            for (int ni = 0; ni < 4; ++ni)
                acc[mi][ni] = __builtin_amdgcn_mfma_f32_16x16x32_bf16(a[mi], b[ni], acc[mi][ni], 0, 0, 0);
        __syncthreads();
    }

    if (tid < 128) rowsum[tid] = 0.f;
    __syncthreads();

    float rowpart[16];   // [mi*4+rg] = sum over this thread's 4 cols
    #pragma unroll
    for (int i = 0; i < 16; ++i) rowpart[i] = 0.f;

    #pragma unroll
    for (int mi = 0; mi < 4; ++mi)
        #pragma unroll
        for (int ni = 0; ni < 4; ++ni) {
            int n = n0 + wn + ni * 16 + r_;
            float bv = bias[n];
            #pragma unroll
            for (int rg = 0; rg < 4; ++rg) {
                int m = m0 + wm + mi * 16 + q * 4 + rg;
                float e = __expf(acc[mi][ni][rg] + bv);
                if (E_BF16)
                    ((unsigned short*)E)[(size_t)m * VV + n] = f2bf(e);
                else
                    ((float*)E)[(size_t)m * VV + n] = e;
                rowpart[mi * 4 + rg] += e;
            }
        }
    // reduce across the 16 lanes of each quad-row group
    #pragma unroll
    for (int i = 0; i < 16; ++i) {
        float v = rowpart[i];
        v += __shfl_xor(v, 1, 64);
        v += __shfl_xor(v, 2, 64);
        v += __shfl_xor(v, 4, 64);
        v += __shfl_xor(v, 8, 64);
        rowpart[i] = v;
    }
    if (r_ == 0) {
        #pragma unroll
        for (int mi = 0; mi < 4; ++mi)
            #pragma unroll
            for (int rg = 0; rg < 4; ++rg)
                atomicAdd(&rowsum[wm + mi * 16 + q * 4 + rg], rowpart[mi * 4 + rg]);
    }
    __syncthreads();
    if (tid < 128) Zpart[(size_t)blockIdx.x * MM + m0 + tid] = rowsum[tid];
}

// ---------------- Z[row] = sum over nblk of Zpart ----------------
__global__ __launch_bounds__(256) void zfinal_kernel(const float* __restrict__ Zpart,
                                                     float* __restrict__ Z) {
    int row = blockIdx.x * 256 + threadIdx.x;
    float s = 0.f;
    for (int nb = 0; nb < NBLK; ++nb) s += Zpart[(size_t)nb * MM + row];
    Z[row] = s;
}

// ---------------- finalize: out = log(pg/Z * E + scatter((1-pg)*attn) + 1e-12) ----------------
// 8 parts per row, CH=4000 columns per block, dense LDS accumulator.
template <bool E_BF16>
__global__ __launch_bounds__(256) void finalize_kernel(const void* __restrict__ E,
                                                       float* __restrict__ out,
                                                       const float* __restrict__ pg_arr,
                                                       const float* __restrict__ Z,
                                                       const float* __restrict__ attn,
                                                       const int* __restrict__ enc) {
    constexpr int CH = VV / 8;  // 4000
    __shared__ float acc[CH];
    int bid = blockIdx.x;
    int row = bid >> 3;
    int part = bid & 7;
    int nbase = part * CH;
    f32x4* acc4 = (f32x4*)acc;
    for (int j = threadIdx.x; j < CH / 4; j += 256) acc4[j] = (f32x4){0.f, 0.f, 0.f, 0.f};
    float pg = pg_arr[row];
    float scale = pg / Z[row];
    float om = 1.f - pg;
    int batch = row / TT;
    __syncthreads();
    for (int s = threadIdx.x; s < SS; s += 256) {
        int idx = enc[batch * SS + s];
        if (idx >= nbase && idx < nbase + CH)
            atomicAdd(&acc[idx - nbase], om * attn[(size_t)row * SS + s]);
    }
    __syncthreads();
    size_t base = (size_t)row * VV + nbase;
    for (int j = threadIdx.x * 8; j < CH; j += 2048) {
        float e[8];
        if (E_BF16) {
            ushort8 u = *(const ushort8*)((const unsigned short*)E + base + j);
            #pragma unroll
            for (int i = 0; i < 8; ++i) e[i] = bf2f(u[i]);
        } else {
            f32x4 u0 = *(const f32x4*)((const float*)E + base + j);
            f32x4 u1 = *(const f32x4*)((const float*)E + base + j + 4);
            e[0]=u0[0]; e[1]=u0[1]; e[2]=u0[2]; e[3]=u0[3];
            e[4]=u1[0]; e[5]=u1[1]; e[6]=u1[2]; e[7]=u1[3];
        }
        f32x4 o0, o1;
        #pragma unroll
        for (int i = 0; i < 4; ++i) o0[i] = __logf(scale * e[i]     + acc[j + i]     + 1e-12f);
        #pragma unroll
        for (int i = 0; i < 4; ++i) o1[i] = __logf(scale * e[4 + i] + acc[j + 4 + i] + 1e-12f);
        *(f32x4*)(out + base + j)     = o0;
        *(f32x4*)(out + base + j + 4) = o1;
    }
}

extern "C" void kernel_launch(void* const* d_in, const int* in_sizes, int n_in,
                              void* d_out, int out_size, void* d_ws, size_t ws_size,
                              hipStream_t stream) {
    const float* s_output = (const float*)d_in[0];
    const float* state_in = (const float*)d_in[1];
    const float* attn     = (const float*)d_in[2];
    const int*   enc      = (const int*)  d_in[3];
    const float* w_pgen   = (const float*)d_in[4];
    const float* b_pgen   = (const float*)d_in[5];
    const float* w1       = (const float*)d_in[6];
    const float* b1       = (const float*)d_in[7];
    const float* w2       = (const float*)d_in[8];
    const float* b2       = (const float*)d_in[9];

    // workspace layout (bytes). Zpart aliases sA (sA dead after gemm1).
    char* ws = (char*)d_ws;
    float*          pg     = (float*)(ws + 0);                 // 2048 f32
    float*          Z      = (float*)(ws + 8192);              // 2048 f32
    unsigned short* hidden = (unsigned short*)(ws + 16384);    // 2048x512 bf16
    unsigned short* sA     = (unsigned short*)(ws + 2113536);  // 2048x512 bf16
    float*          Zpart  = (float*)(ws + 2113536);           // 250x2048 f32 (aliases sA)
    unsigned short* w1t    = (unsigned short*)(ws + 4210688);  // 512x512 bf16
    unsigned short* w2t    = (unsigned short*)(ws + 4734976);  // 32000x512 bf16 (end 37,502,976)
    unsigned short* Ebf    = (unsigned short*)(ws + 37502976); // 2048x32000 bf16 (needs big ws)

    const size_t NEED_BIG = 37502976ull + 2ull * MM * VV;      // 168,574,976
    const bool big = (ws_size >= NEED_BIG);

    f32_to_bf16_kernel<<<(MM * HH / 4 + 255) / 256, 256, 0, stream>>>(s_output, sA, MM * HH / 4);
    transpose_bf16_kernel<<<dim3(HH / 32, KK / 32), 256, 0, stream>>>(w1, w1t, KK, HH);
    transpose_bf16_kernel<<<dim3(VV / 32, KK / 32), 256, 0, stream>>>(w2, w2t, KK, VV);
    pgen_kernel<<<MM / 4, 256, 0, stream>>>(state_in, w_pgen, b_pgen, pg);
    gemm1_kernel<<<dim3(HH / 128, MM / 128), 256, 0, stream>>>(sA, w1t, b1, hidden, HH);

    if (big) {
        gemm2_exp_kernel<true><<<dim3(NBLK, MM / 128), 256, 0, stream>>>(hidden, w2t, b2, Ebf, Zpart);
        zfinal_kernel<<<MM / 256, 256, 0, stream>>>(Zpart, Z);
        finalize_kernel<true><<<MM * 8, 256, 0, stream>>>(Ebf, (float*)d_out, pg, Z, attn, enc);
    } else {
        gemm2_exp_kernel<false><<<dim3(NBLK, MM / 128), 256, 0, stream>>>(hidden, w2t, b2, d_out, Zpart);
        zfinal_kernel<<<MM / 256, 256, 0, stream>>>(Zpart, Z);
        finalize_kernel<false><<<MM * 8, 256, 0, stream>>>(d_out, (float*)d_out, pg, Z, attn, enc);
    }
}